// Round 3
// baseline (569.237 us; speedup 1.0000x reference)
//
#include <hip/hip_runtime.h>

// Problem constants (B,S,E,H,DK,DV,DF) = (4,2048,512,8,64,64,2048)
#define Bx  4
#define Sx  2048
#define Ex  512
#define Hx  8
#define Tt  (Bx * Sx)          // 8192 tokens

typedef short          short8 __attribute__((ext_vector_type(8)));  // 8 bf16
typedef float          f32x4  __attribute__((ext_vector_type(4)));  // MFMA C/D
typedef unsigned short u16;

__device__ __forceinline__ u16 f2bf(float f) {
    unsigned int u = __float_as_uint(f);
    u += 0x7fffu + ((u >> 16) & 1u);          // round-to-nearest-even
    return (u16)(u >> 16);
}
__device__ __forceinline__ float bf2f(u16 h) {
    return __uint_as_float(((unsigned int)h) << 16);
}

// ---------------------------------------------------------------------------
// fp32 -> bf16 flat convert, two tensors in one dispatch (grid.y selects).
// ---------------------------------------------------------------------------
__global__ __launch_bounds__(256) void f32_to_bf16_2(const float* __restrict__ a,
                                                     const float* __restrict__ b,
                                                     u16* __restrict__ oa,
                                                     u16* __restrict__ ob)
{
    const float* in  = blockIdx.y ? b : a;
    u16*         out = blockIdx.y ? ob : oa;
    int i = (blockIdx.x * 256 + threadIdx.x) << 2;
    float4 v = *(const float4*)(in + i);
    ushort4 o;
    o.x = f2bf(v.x); o.y = f2bf(v.y); o.z = f2bf(v.z); o.w = f2bf(v.w);
    *(ushort4*)(out + i) = o;
}

// ---------------------------------------------------------------------------
// W (K x N fp32) -> Wt (N x K bf16). Generic (for ff_W1/ff_W2).
// ---------------------------------------------------------------------------
__global__ __launch_bounds__(256) void transpose_bf16(const float* __restrict__ W,
                                                      u16* __restrict__ Wt,
                                                      int K, int N)
{
    __shared__ u16 tile[32][33];
    const int n0 = blockIdx.x * 32, k0 = blockIdx.y * 32;
    const int tx = threadIdx.x & 31, ty = threadIdx.x >> 5;   // ty 0..7
#pragma unroll
    for (int i = 0; i < 32; i += 8)
        tile[ty + i][tx] = f2bf(W[(size_t)(k0 + ty + i) * N + n0 + tx]);
    __syncthreads();
#pragma unroll
    for (int i = 0; i < 32; i += 8)
        Wt[(size_t)(n0 + ty + i) * K + k0 + tx] = tile[tx][ty + i];
}

// ---------------------------------------------------------------------------
// 8x 512x512 transposes in one dispatch; slot z writes base + z*262144.
// ---------------------------------------------------------------------------
struct WPtrs { const float* w[8]; };
__global__ __launch_bounds__(256) void transpose8_bf16(WPtrs ws, u16* __restrict__ base)
{
    __shared__ u16 tile[32][33];
    const float* W  = ws.w[blockIdx.z];
    u16*         Wt = base + (size_t)blockIdx.z * 262144;
    const int n0 = blockIdx.x * 32, k0 = blockIdx.y * 32;
    const int tx = threadIdx.x & 31, ty = threadIdx.x >> 5;
#pragma unroll
    for (int i = 0; i < 32; i += 8)
        tile[ty + i][tx] = f2bf(W[(size_t)(k0 + ty + i) * 512 + n0 + tx]);
    __syncthreads();
#pragma unroll
    for (int i = 0; i < 32; i += 8)
        Wt[(size_t)(n0 + ty + i) * 512 + k0 + tx] = tile[tx][ty + i];
}

// ---------------------------------------------------------------------------
// gemm128: 128x128 tile, BK=32, 256 thr = 4 waves (2x2), wave 64x64.
// ---------------------------------------------------------------------------
template<int OUT_BF16, int RELU>
__global__ __launch_bounds__(256) void gemm128(const u16* __restrict__ A,
                                               const u16* __restrict__ Bt,
                                               const float* __restrict__ b0,
                                               const float* __restrict__ b1,
                                               const float* __restrict__ b2,
                                               const float* __restrict__ b3,
                                               void* __restrict__ Cout,
                                               int M, int N, int K, int ldc)
{
    __shared__ u16 As[128 * 40];
    __shared__ u16 Bs[128 * 40];

    const int tid  = threadIdx.x;
    const int w    = tid >> 6;
    const int lane = tid & 63;
    const int c    = lane & 15;
    const int quad = lane >> 4;
    const int wr   = w >> 1, wc = w & 1;
    const int m0   = blockIdx.y * 128;
    const int n0   = blockIdx.x * 128;

    const int row0 = tid >> 2;           // 0..63
    const int kc   = (tid & 3) << 3;     // 0,8,16,24

    const u16* Ap = A  + (size_t)(m0 + row0) * K + kc;
    const u16* Bp = Bt + (size_t)(n0 + row0) * K + kc;
    const size_t rstep = (size_t)64 * K;

    f32x4 acc[4][4];
#pragma unroll
    for (int i = 0; i < 4; i++)
#pragma unroll
        for (int j = 0; j < 4; j++) { acc[i][j][0]=0.f; acc[i][j][1]=0.f; acc[i][j][2]=0.f; acc[i][j][3]=0.f; }

    short8 ra0 = *(const short8*)(Ap);
    short8 ra1 = *(const short8*)(Ap + rstep);
    short8 rb0 = *(const short8*)(Bp);
    short8 rb1 = *(const short8*)(Bp + rstep);

    for (int k0 = 0; k0 < K; k0 += 32) {
        __syncthreads();
        *(short8*)&As[row0 * 40 + kc]        = ra0;
        *(short8*)&As[(row0 + 64) * 40 + kc] = ra1;
        *(short8*)&Bs[row0 * 40 + kc]        = rb0;
        *(short8*)&Bs[(row0 + 64) * 40 + kc] = rb1;
        __syncthreads();

        if (k0 + 32 < K) {
            ra0 = *(const short8*)(Ap + k0 + 32);
            ra1 = *(const short8*)(Ap + rstep + k0 + 32);
            rb0 = *(const short8*)(Bp + k0 + 32);
            rb1 = *(const short8*)(Bp + rstep + k0 + 32);
        }

        short8 af[4], bf[4];
#pragma unroll
        for (int i = 0; i < 4; i++)
            af[i] = *(const short8*)&As[(wr * 64 + i * 16 + c) * 40 + quad * 8];
#pragma unroll
        for (int j = 0; j < 4; j++)
            bf[j] = *(const short8*)&Bs[(wc * 64 + j * 16 + c) * 40 + quad * 8];
#pragma unroll
        for (int i = 0; i < 4; i++)
#pragma unroll
            for (int j = 0; j < 4; j++)
                acc[i][j] = __builtin_amdgcn_mfma_f32_16x16x32_bf16(af[i], bf[j], acc[i][j], 0, 0, 0);
    }

    // ---- epilogue ----
    const int seg = n0 >> 9;
    const float* bp = seg == 0 ? b0 : (seg == 1 ? b1 : (seg == 2 ? b2 : b3));
    const int nbase = n0 & 511;
    float bv[4];
#pragma unroll
    for (int j = 0; j < 4; j++) bv[j] = bp[nbase + wc * 64 + j * 16 + c];

#pragma unroll
    for (int i = 0; i < 4; i++) {
#pragma unroll
        for (int j = 0; j < 4; j++) {
            int colg = n0 + wc * 64 + j * 16 + c;
#pragma unroll
            for (int r = 0; r < 4; r++) {
                int rowg = m0 + wr * 64 + i * 16 + quad * 4 + r;
                float v = acc[i][j][r] + bv[j];
                if (RELU) v = fmaxf(v, 0.f);
                if (OUT_BF16) ((u16*)Cout)[(size_t)rowg * ldc + colg] = f2bf(v);
                else          ((float*)Cout)[(size_t)rowg * ldc + colg] = v;
            }
        }
    }
}

// ---------------------------------------------------------------------------
// gemm64: 128x64 tile, BK=32, 128 thr = 2 waves.
// ---------------------------------------------------------------------------
template<int OUT_BF16, int RELU>
__global__ __launch_bounds__(128) void gemm64(const u16* __restrict__ A,
                                              const u16* __restrict__ Bt,
                                              const float* __restrict__ bias,
                                              void* __restrict__ Cout,
                                              int M, int N, int K, int ldc)
{
    __shared__ u16 As[128 * 40];
    __shared__ u16 Bs[64 * 40];

    const int tid  = threadIdx.x;
    const int w    = tid >> 6;
    const int lane = tid & 63;
    const int c    = lane & 15;
    const int quad = lane >> 4;
    const int m0   = blockIdx.y * 128;
    const int n0   = blockIdx.x * 64;

    const int rA = tid >> 2;            // 0..31
    const int kc = (tid & 3) << 3;      // 0,8,16,24

    const u16* Ap = A  + (size_t)(m0 + rA) * K + kc;
    const u16* Bp = Bt + (size_t)(n0 + rA) * K + kc;
    const size_t a32 = (size_t)32 * K;

    f32x4 acc[4][4];
#pragma unroll
    for (int i = 0; i < 4; i++)
#pragma unroll
        for (int j = 0; j < 4; j++) { acc[i][j][0]=0.f; acc[i][j][1]=0.f; acc[i][j][2]=0.f; acc[i][j][3]=0.f; }

    short8 ra[4], rb[2];
#pragma unroll
    for (int i = 0; i < 4; i++) ra[i] = *(const short8*)(Ap + i * a32);
#pragma unroll
    for (int i = 0; i < 2; i++) rb[i] = *(const short8*)(Bp + i * a32);

    for (int k0 = 0; k0 < K; k0 += 32) {
        __syncthreads();
#pragma unroll
        for (int i = 0; i < 4; i++) *(short8*)&As[(rA + i * 32) * 40 + kc] = ra[i];
#pragma unroll
        for (int i = 0; i < 2; i++) *(short8*)&Bs[(rA + i * 32) * 40 + kc] = rb[i];
        __syncthreads();

        if (k0 + 32 < K) {
#pragma unroll
            for (int i = 0; i < 4; i++) ra[i] = *(const short8*)(Ap + i * a32 + k0 + 32);
#pragma unroll
            for (int i = 0; i < 2; i++) rb[i] = *(const short8*)(Bp + i * a32 + k0 + 32);
        }

        short8 af[4], bf[4];
#pragma unroll
        for (int i = 0; i < 4; i++)
            af[i] = *(const short8*)&As[(w * 64 + i * 16 + c) * 40 + quad * 8];
#pragma unroll
        for (int j = 0; j < 4; j++)
            bf[j] = *(const short8*)&Bs[(j * 16 + c) * 40 + quad * 8];
#pragma unroll
        for (int i = 0; i < 4; i++)
#pragma unroll
            for (int j = 0; j < 4; j++)
                acc[i][j] = __builtin_amdgcn_mfma_f32_16x16x32_bf16(af[i], bf[j], acc[i][j], 0, 0, 0);
    }

    float bv[4];
#pragma unroll
    for (int j = 0; j < 4; j++) bv[j] = bias[n0 + j * 16 + c];

#pragma unroll
    for (int i = 0; i < 4; i++) {
#pragma unroll
        for (int j = 0; j < 4; j++) {
            int colg = n0 + j * 16 + c;
#pragma unroll
            for (int r = 0; r < 4; r++) {
                int rowg = m0 + w * 64 + i * 16 + quad * 4 + r;
                float v = acc[i][j][r] + bv[j];
                if (RELU) v = fmaxf(v, 0.f);
                if (OUT_BF16) ((u16*)Cout)[(size_t)rowg * ldc + colg] = f2bf(v);
                else          ((float*)Cout)[(size_t)rowg * ldc + colg] = v;
            }
        }
    }
}

// ---------------------------------------------------------------------------
// MFMA flash attention, v4: 32 queries per wave (LDS-amortized).
//   Post-mortem v3: prefetch + swizzle left dur at v1's 105us and FETCH at
//   12MB -> never latency/BW-bound. Arithmetic: ~10 b128 + 8 b32 LDS instrs
//   per wave per 32-key tile x 16 waves/CU x ~12/5.8 cy ~= 2700 cy/CU/tile
//   ~= the measured time => single per-CU LDS pipe is the bottleneck.
//   v4: each wave owns 32 queries (two 16-row A-frags a=0,1). The K-frag and
//   V-frag b128 reads (identical across queries) now feed 16 MFMAs instead
//   of 8 -> b128 traffic per query halves. Block = 4 waves x 32q = 128 q;
//   grid (16,32) = 512 blocks = 2/CU.
//   Kept: XCD swizzle (8 XCDs x 4 bh-groups x 16 qtiles, bijective),
//   aligned LDS strides (72/40 u16 rows, 16B multiples), single-b128 V
//   staging via 8 coalesced gathers, register prefetch, volatile wave-local
//   P round-trip (Plds now 32 rows/wave, odd u32 stride 19), per-frag causal
//   skip now per (wave, a-frag): fm0/fm1 live 16-key frag counts.
// No max-subtraction (|s|<~2): unnormalized O += P*V, l += sum(exp) ==
// reference softmax; p=0 == exp(-1e9) underflow.
// Layouts (m89/m91): A[m=lane&15][k=quad*8+j], B[k=quad*8+j][n=lane&15],
// C/D: col=lane&15, row=quad*4+reg.
// ---------------------------------------------------------------------------
template<bool CAUSAL>
__global__ __launch_bounds__(256) void attn_mfma(const u16* __restrict__ Q,
                                                 const u16* __restrict__ K,
                                                 const u16* __restrict__ V,
                                                 u16* __restrict__ O,
                                                 int ldq, int ldk, int ldv)
{
    __shared__ u16          Klds[32 * 72];       // [key][dim], 144B rows
    __shared__ u16          Vtlds[64 * 40];      // [dim][pi-pos], 80B rows
    __shared__ unsigned int Plds[4][32 * 19];    // per-wave [q 0..31][pi-word]

    const int tid  = threadIdx.x;
    const int w    = tid >> 6;
    const int lane = tid & 63;
    const int c    = lane & 15;
    const int quad = lane >> 4;

    // XCD-aware swizzle; grid (16, 32) = 512 blocks = 8 XCDs * 64.
    const int flat = blockIdx.y * 16 + blockIdx.x;
    const int idx  = flat >> 3;                     // 0..63 within XCD
    const int bh   = (flat & 7) * 4 + (idx >> 4);   // 4 bh groups per XCD
    const int q0   = (idx & 15) * 128;

    const int b    = bh >> 3;
    const int h    = bh & 7;
    const int bS   = b * Sx;
    const int hoff = h * 64;
    const int qw   = q0 + w * 32;                // wave's first query (32 q/wave)

    // K staging: thread owns (key = tid>>3, dim chunk (tid&7)*8)
    const int kkey = tid >> 3;
    const int kc8  = (tid & 7) << 3;
    // V staging: thread owns (dim = tid&63, pi-pos block (tid>>6)*8)
    const int vdim = tid & 63;
    const int vp   = (tid >> 6) << 3;

    short8 qa[2][2];                             // [a-frag][k-half]
#pragma unroll
    for (int a = 0; a < 2; a++) {
        const u16* qp = Q + (size_t)(bS + qw + a * 16 + c) * ldq + hoff;
        qa[a][0] = *(const short8*)(qp + quad * 8);
        qa[a][1] = *(const short8*)(qp + 32 + quad * 8);
    }

    f32x4 of[2][4];
#pragma unroll
    for (int a = 0; a < 2; a++)
#pragma unroll
        for (int f = 0; f < 4; f++) { of[a][f][0]=0.f; of[a][f][1]=0.f; of[a][f][2]=0.f; of[a][f][3]=0.f; }
    float lpart[2][4] = {{0.f,0.f,0.f,0.f},{0.f,0.f,0.f,0.f}};

    const int kend = CAUSAL ? (q0 + 128) : Sx;

    // global staging pointers (per-thread, advance by kt)
    const u16* Kgp = K + (size_t)(bS + kkey) * ldk + hoff + kc8;
    const u16* Vgp = V + (size_t)bS * ldv + hoff + vdim;

    // ---- prologue: prefetch tile 0 into registers ----
    short8 kr = *(const short8*)(Kgp);
    union { short8 v; u16 u[8]; } vb;
#pragma unroll
    for (int j = 0; j < 8; j++) {
        int pos = vp + j;
        int key = (pos >> 1) + ((pos & 1) << 4);
        vb.u[j] = Vgp[(size_t)key * ldv];
    }

    for (int kt = 0; kt < kend; kt += 32) {
        __syncthreads();                         // (1) WAR: prior reads done
        *(short8*)&Klds[kkey * 72 + kc8] = kr;   // stage K row (b128)
        *(short8*)&Vtlds[vdim * 40 + vp] = vb.v; // stage V^T pi-block (b128)
        __syncthreads();                         // (2) staging ready

        // ---- prefetch next tile (overlaps the compute below) ----
        if (kt + 32 < kend) {
            kr = *(const short8*)(Kgp + (size_t)(kt + 32) * ldk);
#pragma unroll
            for (int j = 0; j < 8; j++) {
                int pos = vp + j;
                int key = kt + 32 + (pos >> 1) + ((pos & 1) << 4);
                vb.u[j] = Vgp[(size_t)key * ldv];
            }
        }

        int fm0 = 2, fm1 = 2;                    // live 16-key frags per a-frag
        if (CAUSAL) {
            int d0 = ((qw + 15 - kt) >> 4) + 1;  // arithmetic shift: can be <=0
            int d1 = ((qw + 31 - kt) >> 4) + 1;
            fm0 = d0 < 2 ? d0 : 2;
            fm1 = d1 < 2 ? d1 : 2;               // fm1 >= fm0
        }

        if (fm1 > 0) {                           // wave has any live keys
            // ---- K frag reads, shared across both a-frags ----
            short8 kb[2][2];
#pragma unroll
            for (int f = 0; f < 2; f++) {
                if (f < fm1) {
                    kb[f][0] = *(const short8*)&Klds[(f * 16 + c) * 72 + quad * 8];
                    kb[f][1] = *(const short8*)&Klds[(f * 16 + c) * 72 + 32 + quad * 8];
                }
            }

            // ---- S = Q K^T for live (a, f) pairs ----
            f32x4 s[2][2];
#pragma unroll
            for (int a = 0; a < 2; a++) {
                const int fma_ = a ? fm1 : fm0;
#pragma unroll
                for (int f = 0; f < 2; f++) {
                    if (f < fma_) {
                        f32x4 z; z[0]=0.f; z[1]=0.f; z[2]=0.f; z[3]=0.f;
                        z = __builtin_amdgcn_mfma_f32_16x16x32_bf16(qa[a][0], kb[f][0], z, 0, 0, 0);
                        z = __builtin_amdgcn_mfma_f32_16x16x32_bf16(qa[a][1], kb[f][1], z, 0, 0, 0);
                        s[a][f] = z;
                    }
                }
            }

            // ---- P = exp(S/8), pi-packed u32, volatile store (wave-local) ----
#pragma unroll
            for (int a = 0; a < 2; a++) {
                const int fma_ = a ? fm1 : fm0;
                if (fma_ > 0) {
#pragma unroll
                    for (int r = 0; r < 4; r++) {
                        int qg = qw + a * 16 + quad * 4 + r;
                        float p0 = 0.f, p1 = 0.f;
                        if (!(CAUSAL && (kt + c) > qg))
                            p0 = __expf(s[a][0][r] * 0.125f);
                        if (fma_ > 1 && !(CAUSAL && (kt + 16 + c) > qg))
                            p1 = __expf(s[a][1][r] * 0.125f);
                        u16 b0 = f2bf(p0), b1 = f2bf(p1);
                        lpart[a][r] += bf2f(b0) + bf2f(b1);
                        *(volatile unsigned int*)&Plds[w][(a * 16 + quad * 4 + r) * 19 + c] =
                            (unsigned int)b0 | ((unsigned int)b1 << 16);
                    }
                }
            }

            // ---- P readback (volatile, ordered after the stores) ----
            union { unsigned int u[4]; short8 s8; } pu0, pu1;
            if (fm0 > 0) {
#pragma unroll
                for (int i = 0; i < 4; i++)
                    pu0.u[i] = *(volatile const unsigned int*)&Plds[w][c * 19 + quad * 4 + i];
            }
#pragma unroll
            for (int i = 0; i < 4; i++)
                pu1.u[i] = *(volatile const unsigned int*)&Plds[w][(16 + c) * 19 + quad * 4 + i];

            // ---- O += P * V (V frag shared across both a-frags) ----
#pragma unroll
            for (int f2 = 0; f2 < 4; f2++) {
                short8 vbf = *(const short8*)&Vtlds[(f2 * 16 + c) * 40 + quad * 8];
                if (fm0 > 0)
                    of[0][f2] = __builtin_amdgcn_mfma_f32_16x16x32_bf16(pu0.s8, vbf, of[0][f2], 0, 0, 0);
                of[1][f2] = __builtin_amdgcn_mfma_f32_16x16x32_bf16(pu1.s8, vbf, of[1][f2], 0, 0, 0);
            }
        }
    }

    // ---- denominators: sum over the quad's 16 lanes ----
#pragma unroll
    for (int a = 0; a < 2; a++)
#pragma unroll
        for (int r = 0; r < 4; r++) {
            float v = lpart[a][r];
            v += __shfl_xor(v, 1, 64);
            v += __shfl_xor(v, 2, 64);
            v += __shfl_xor(v, 4, 64);
            v += __shfl_xor(v, 8, 64);
            lpart[a][r] = 1.f / v;
        }

    // ---- write O (bf16, stride 512): row = a*16+quad*4+r, col = f*16+c ----
    u16* Ob = O + (size_t)(bS + qw) * Ex + hoff;
#pragma unroll
    for (int a = 0; a < 2; a++)
#pragma unroll
        for (int f = 0; f < 4; f++)
#pragma unroll
            for (int r = 0; r < 4; r++)
                Ob[(size_t)(a * 16 + quad * 4 + r) * Ex + f * 16 + c] =
                    f2bf(of[a][f][r] * lpart[a][r]);
}

// ---------------------------------------------------------------------------
// Fused residual-add + LayerNorm over E=512; fp32 out + optional bf16 copy.
// ---------------------------------------------------------------------------
__global__ __launch_bounds__(256) void ln_add(const float* __restrict__ x,
                                              const float* __restrict__ s,
                                              const float* __restrict__ g,
                                              const float* __restrict__ bta,
                                              float* __restrict__ out,
                                              u16* __restrict__ out_bf)
{
    __shared__ float red[8];
    const int    row  = blockIdx.x;
    const int    t    = threadIdx.x;
    const size_t base = (size_t)row * Ex;

    float2 xv = *(const float2*)(x + base + (t << 1));
    float2 sv = *(const float2*)(s + base + (t << 1));
    float  y0 = xv.x + sv.x;
    float  y1 = xv.y + sv.y;

    float sum = y0 + y1;
    float sq  = y0 * y0 + y1 * y1;
#pragma unroll
    for (int o = 32; o > 0; o >>= 1) {
        sum += __shfl_down(sum, o, 64);
        sq  += __shfl_down(sq,  o, 64);
    }
    const int wid = t >> 6, lane = t & 63;
    if (lane == 0) { red[wid] = sum; red[4 + wid] = sq; }
    __syncthreads();
    if (t == 0) {
        red[0] = red[0] + red[1] + red[2] + red[3];
        red[4] = red[4] + red[5] + red[6] + red[7];
    }
    __syncthreads();

    const float mean = red[0] * (1.f / 512.f);
    const float var  = red[4] * (1.f / 512.f) - mean * mean;
    const float rstd = rsqrtf(var + 1e-3f);

    float2 gv = *(const float2*)(g   + (t << 1));
    float2 bv = *(const float2*)(bta + (t << 1));
    float  o0 = (y0 - mean) * rstd * gv.x + bv.x;
    float  o1 = (y1 - mean) * rstd * gv.y + bv.y;
    *(float2*)(out + base + (t << 1)) = make_float2(o0, o1);
    if (out_bf) {
        ushort2 ob; ob.x = f2bf(o0); ob.y = f2bf(o1);
        *(ushort2*)(out_bf + base + (t << 1)) = ob;
    }
}

// ---------------------------------------------------------------------------
// Orchestration. 96 MB workspace, byte offsets (MB):
//   [0,8)   bw: bf16 W^T x10 (8 square slots contiguous, then ff1, ff2)
//   [8,16)  xb     | P3: x2f = [8,24) fp32
//   [16,24) encb
//   [24,48) qkvB (stride 1536) | P2: qb=[24,32) str512, kvB=[32,48) str1024
//            | P3: ff1b = [24,56)
//   [48,56) ob (attn out, stride 512)
//   [56,72) projF fp32 (also ff2 out)
//   [72,88) x1f fp32
//   [88,96) x1b | P3: x2b
// ---------------------------------------------------------------------------
extern "C" void kernel_launch(void* const* d_in, const int* in_sizes, int n_in,
                              void* d_out, int out_size, void* d_ws, size_t ws_size,
                              hipStream_t stream)
{
    const float* x     = (const float*)d_in[0];
    const float* enc   = (const float*)d_in[1];
    const float* sa_Wq = (const float*)d_in[4],  *sa_bq = (const float*)d_in[5];
    const float* sa_Wk = (const float*)d_in[6],  *sa_bk = (const float*)d_in[7];
    const float* sa_Wv = (const float*)d_in[8],  *sa_bv = (const float*)d_in[9];
    const float* sa_Wo = (const float*)d_in[10], *sa_bo = (const float*)d_in[11];
    const float* ca_Wq = (const float*)d_in[12], *ca_bq = (const float*)d_in[13];
    const float* ca_Wk = (const float*)d_in[14], *ca_bk = (const float*)d_in[15];
    const float* ca_Wv = (const float*)d_in[16], *ca_bv = (const float*)d_in[17];
    const float* ca_Wo = (const float*)d_in[18], *ca_bo = (const float*)d_in[19];
    const float* ff_W1 = (const float*)d_in[20], *ff_b1 = (const float*)d_in[21];
    const float* ff_W2 = (const float*)d_in[22], *ff_b2 = (const float*)d_in[23];
    const float* ln1_g = (const float*)d_in[24], *ln1_b = (const float*)d_in[25];
    const float* ln2_g = (const float*)d_in[26], *ln2_b = (const float*)d_in[27];
    const float* ln3_g = (const float*)d_in[28], *ln3_b = (const float*)d_in[29];

    char* ws = (char*)d_ws;
    const size_t MB = 1024 * 1024;
    u16*   bw   = (u16*)(ws);
    u16*   xb   = (u16*)(ws + 8  * MB);
    u16*   encb = (u16*)(ws + 16 * MB);
    u16*   qkvB = (u16*)(ws + 24 * MB);
    u16*   qb   = (u16*)(ws + 24 * MB);
    u16*   kvB  = (u16*)(ws + 32 * MB);
    u16*   ff1b = (u16*)(ws + 24 * MB);
    u16*   ob   = (u16*)(ws + 48 * MB);
    float* projF= (float*)(ws + 56 * MB);
    float* x1f  = (float*)(ws + 72 * MB);
    u16*   x1b  = (u16*)(ws + 88 * MB);
    u16*   x2b  = (u16*)(ws + 88 * MB);
    float* x2f  = (float*)(ws + 8  * MB);

    // bf16 W^T slots: 8 squares contiguous (transpose8 order), then ff1/ff2
    u16* wsaq = bw;                 // QKV fused Bt = rows 0..1535 (q,k,v)
    u16* wsao = bw + 786432;
    u16* wcaq = bw + 1048576;
    u16* wcak = bw + 1310720;       // caKV fused Bt = rows 0..1023 (k,v)
    u16* wcao = bw + 1835008;
    u16* wff1 = bw + 2097152;
    u16* wff2 = bw + 3145728;

    // ---- pre-pass (4 launches) ----
    f32_to_bf16_2<<<dim3(Tt * Ex / 1024, 2), dim3(256), 0, stream>>>(x, enc, xb, encb);
    WPtrs wp; wp.w[0]=sa_Wq; wp.w[1]=sa_Wk; wp.w[2]=sa_Wv; wp.w[3]=sa_Wo;
    wp.w[4]=ca_Wq; wp.w[5]=ca_Wk; wp.w[6]=ca_Wv; wp.w[7]=ca_Wo;
    transpose8_bf16<<<dim3(16, 16, 8), dim3(256), 0, stream>>>(wp, bw);
    transpose_bf16<<<dim3(64, 16), dim3(256), 0, stream>>>(ff_W1, wff1, 512, 2048);
    transpose_bf16<<<dim3(16, 64), dim3(256), 0, stream>>>(ff_W2, wff2, 2048, 512);

    auto G128 = [&](const u16* A, const u16* Wt, const float* b0, const float* b1,
                    const float* b2, const float* b3, void* C,
                    int N, int K, int ldc, int out_bf, int relu) {
        dim3 grid(N / 128, Tt / 128);
        if (out_bf) {
            if (relu) gemm128<1,1><<<grid, dim3(256), 0, stream>>>(A, Wt, b0,b1,b2,b3, C, Tt, N, K, ldc);
            else      gemm128<1,0><<<grid, dim3(256), 0, stream>>>(A, Wt, b0,b1,b2,b3, C, Tt, N, K, ldc);
        } else        gemm128<0,0><<<grid, dim3(256), 0, stream>>>(A, Wt, b0,b1,b2,b3, C, Tt, N, K, ldc);
    };
    auto G64 = [&](const u16* A, const u16* Wt, const float* bi, void* C,
                   int K, int ldc, int out_bf) {
        dim3 grid(512 / 64, Tt / 128);
        if (out_bf) gemm64<1,0><<<grid, dim3(128), 0, stream>>>(A, Wt, bi, C, Tt, 512, K, ldc);
        else        gemm64<0,0><<<grid, dim3(128), 0, stream>>>(A, Wt, bi, C, Tt, 512, K, ldc);
    };
    const dim3 agrid(Sx / 128, Bx * Hx);    // (16, 32) = 512 blocks

    // ---- stage 1: fused QKV GEMM + self-attn + add&norm ----
    G128(xb, wsaq, sa_bq, sa_bk, sa_bv, sa_bv, qkvB, 1536, 512, 1536, 1, 0);
    attn_mfma<true><<<agrid, dim3(256), 0, stream>>>(qkvB, qkvB + 512, qkvB + 1024,
                                                     ob, 1536, 1536, 1536);
    G64(ob, wsao, sa_bo, projF, 512, 512, 0);
    ln_add<<<dim3(Tt), dim3(256), 0, stream>>>(x, projF, ln1_g, ln1_b, x1f, x1b);

    // ---- stage 2: cross-attention + add&norm ----
    G64(x1b, wcaq, ca_bq, qb, 512, 512, 1);
    G128(encb, wcak, ca_bk, ca_bv, ca_bv, ca_bv, kvB, 1024, 512, 1024, 1, 0);
    attn_mfma<false><<<agrid, dim3(256), 0, stream>>>(qb, kvB, kvB + 512,
                                                      ob, 512, 1024, 1024);
    G64(ob, wcao, ca_bo, projF, 512, 512, 0);
    ln_add<<<dim3(Tt), dim3(256), 0, stream>>>(x1f, projF, ln2_g, ln2_b, x2f, x2b);

    // ---- stage 3: FFN + add&norm ----
    G128(x2b, wff1, ff_b1, ff_b1 + 512, ff_b1 + 1024, ff_b1 + 1536,
         ff1b, 2048, 512, 2048, 1, 1);                       // ReLU
    G64(ff1b, wff2, ff_b2, projF, 2048, 512, 0);
    ln_add<<<dim3(Tt), dim3(256), 0, stream>>>(x2f, projF, ln3_g, ln3_b,
                                               (float*)d_out, (u16*)nullptr);
}

// Round 4
// 507.345 us; speedup vs baseline: 1.1220x; 1.1220x over previous
//
#include <hip/hip_runtime.h>

// Problem constants (B,S,E,H,DK,DV,DF) = (4,2048,512,8,64,64,2048)
#define Bx  4
#define Sx  2048
#define Ex  512
#define Hx  8
#define Tt  (Bx * Sx)          // 8192 tokens

typedef short          short8 __attribute__((ext_vector_type(8)));  // 8 bf16
typedef float          f32x4  __attribute__((ext_vector_type(4)));  // MFMA C/D
typedef unsigned short u16;

__device__ __forceinline__ u16 f2bf(float f) {
    unsigned int u = __float_as_uint(f);
    u += 0x7fffu + ((u >> 16) & 1u);          // round-to-nearest-even
    return (u16)(u >> 16);
}
__device__ __forceinline__ float bf2f(u16 h) {
    return __uint_as_float(((unsigned int)h) << 16);
}

// ---------------------------------------------------------------------------
// fp32 -> bf16 flat convert, two tensors in one dispatch (grid.y selects).
// ---------------------------------------------------------------------------
__global__ __launch_bounds__(256) void f32_to_bf16_2(const float* __restrict__ a,
                                                     const float* __restrict__ b,
                                                     u16* __restrict__ oa,
                                                     u16* __restrict__ ob)
{
    const float* in  = blockIdx.y ? b : a;
    u16*         out = blockIdx.y ? ob : oa;
    int i = (blockIdx.x * 256 + threadIdx.x) << 2;
    float4 v = *(const float4*)(in + i);
    ushort4 o;
    o.x = f2bf(v.x); o.y = f2bf(v.y); o.z = f2bf(v.z); o.w = f2bf(v.w);
    *(ushort4*)(out + i) = o;
}

// ---------------------------------------------------------------------------
// W (K x N fp32) -> Wt (N x K bf16). Generic (for ff_W1/ff_W2).
// ---------------------------------------------------------------------------
__global__ __launch_bounds__(256) void transpose_bf16(const float* __restrict__ W,
                                                      u16* __restrict__ Wt,
                                                      int K, int N)
{
    __shared__ u16 tile[32][33];
    const int n0 = blockIdx.x * 32, k0 = blockIdx.y * 32;
    const int tx = threadIdx.x & 31, ty = threadIdx.x >> 5;   // ty 0..7
#pragma unroll
    for (int i = 0; i < 32; i += 8)
        tile[ty + i][tx] = f2bf(W[(size_t)(k0 + ty + i) * N + n0 + tx]);
    __syncthreads();
#pragma unroll
    for (int i = 0; i < 32; i += 8)
        Wt[(size_t)(n0 + ty + i) * K + k0 + tx] = tile[tx][ty + i];
}

// ---------------------------------------------------------------------------
// 8x 512x512 transposes in one dispatch; slot z writes base + z*262144.
// ---------------------------------------------------------------------------
struct WPtrs { const float* w[8]; };
__global__ __launch_bounds__(256) void transpose8_bf16(WPtrs ws, u16* __restrict__ base)
{
    __shared__ u16 tile[32][33];
    const float* W  = ws.w[blockIdx.z];
    u16*         Wt = base + (size_t)blockIdx.z * 262144;
    const int n0 = blockIdx.x * 32, k0 = blockIdx.y * 32;
    const int tx = threadIdx.x & 31, ty = threadIdx.x >> 5;
#pragma unroll
    for (int i = 0; i < 32; i += 8)
        tile[ty + i][tx] = f2bf(W[(size_t)(k0 + ty + i) * 512 + n0 + tx]);
    __syncthreads();
#pragma unroll
    for (int i = 0; i < 32; i += 8)
        Wt[(size_t)(n0 + ty + i) * 512 + k0 + tx] = tile[tx][ty + i];
}

// ---------------------------------------------------------------------------
// gemm128: 128x128 tile, BK=32, 256 thr = 4 waves (2x2), wave 64x64.
// ---------------------------------------------------------------------------
template<int OUT_BF16, int RELU>
__global__ __launch_bounds__(256) void gemm128(const u16* __restrict__ A,
                                               const u16* __restrict__ Bt,
                                               const float* __restrict__ b0,
                                               const float* __restrict__ b1,
                                               const float* __restrict__ b2,
                                               const float* __restrict__ b3,
                                               void* __restrict__ Cout,
                                               int M, int N, int K, int ldc)
{
    __shared__ u16 As[128 * 40];
    __shared__ u16 Bs[128 * 40];

    const int tid  = threadIdx.x;
    const int w    = tid >> 6;
    const int lane = tid & 63;
    const int c    = lane & 15;
    const int quad = lane >> 4;
    const int wr   = w >> 1, wc = w & 1;
    const int m0   = blockIdx.y * 128;
    const int n0   = blockIdx.x * 128;

    const int row0 = tid >> 2;           // 0..63
    const int kc   = (tid & 3) << 3;     // 0,8,16,24

    const u16* Ap = A  + (size_t)(m0 + row0) * K + kc;
    const u16* Bp = Bt + (size_t)(n0 + row0) * K + kc;
    const size_t rstep = (size_t)64 * K;

    f32x4 acc[4][4];
#pragma unroll
    for (int i = 0; i < 4; i++)
#pragma unroll
        for (int j = 0; j < 4; j++) { acc[i][j][0]=0.f; acc[i][j][1]=0.f; acc[i][j][2]=0.f; acc[i][j][3]=0.f; }

    short8 ra0 = *(const short8*)(Ap);
    short8 ra1 = *(const short8*)(Ap + rstep);
    short8 rb0 = *(const short8*)(Bp);
    short8 rb1 = *(const short8*)(Bp + rstep);

    for (int k0 = 0; k0 < K; k0 += 32) {
        __syncthreads();
        *(short8*)&As[row0 * 40 + kc]        = ra0;
        *(short8*)&As[(row0 + 64) * 40 + kc] = ra1;
        *(short8*)&Bs[row0 * 40 + kc]        = rb0;
        *(short8*)&Bs[(row0 + 64) * 40 + kc] = rb1;
        __syncthreads();

        if (k0 + 32 < K) {
            ra0 = *(const short8*)(Ap + k0 + 32);
            ra1 = *(const short8*)(Ap + rstep + k0 + 32);
            rb0 = *(const short8*)(Bp + k0 + 32);
            rb1 = *(const short8*)(Bp + rstep + k0 + 32);
        }

        short8 af[4], bf[4];
#pragma unroll
        for (int i = 0; i < 4; i++)
            af[i] = *(const short8*)&As[(wr * 64 + i * 16 + c) * 40 + quad * 8];
#pragma unroll
        for (int j = 0; j < 4; j++)
            bf[j] = *(const short8*)&Bs[(wc * 64 + j * 16 + c) * 40 + quad * 8];
#pragma unroll
        for (int i = 0; i < 4; i++)
#pragma unroll
            for (int j = 0; j < 4; j++)
                acc[i][j] = __builtin_amdgcn_mfma_f32_16x16x32_bf16(af[i], bf[j], acc[i][j], 0, 0, 0);
    }

    // ---- epilogue ----
    const int seg = n0 >> 9;
    const float* bp = seg == 0 ? b0 : (seg == 1 ? b1 : (seg == 2 ? b2 : b3));
    const int nbase = n0 & 511;
    float bv[4];
#pragma unroll
    for (int j = 0; j < 4; j++) bv[j] = bp[nbase + wc * 64 + j * 16 + c];

#pragma unroll
    for (int i = 0; i < 4; i++) {
#pragma unroll
        for (int j = 0; j < 4; j++) {
            int colg = n0 + wc * 64 + j * 16 + c;
#pragma unroll
            for (int r = 0; r < 4; r++) {
                int rowg = m0 + wr * 64 + i * 16 + quad * 4 + r;
                float v = acc[i][j][r] + bv[j];
                if (RELU) v = fmaxf(v, 0.f);
                if (OUT_BF16) ((u16*)Cout)[(size_t)rowg * ldc + colg] = f2bf(v);
                else          ((float*)Cout)[(size_t)rowg * ldc + colg] = v;
            }
        }
    }
}

// ---------------------------------------------------------------------------
// gemm64: 128x64 tile, BK=32, 128 thr = 2 waves.
// ---------------------------------------------------------------------------
template<int OUT_BF16, int RELU>
__global__ __launch_bounds__(128) void gemm64(const u16* __restrict__ A,
                                              const u16* __restrict__ Bt,
                                              const float* __restrict__ bias,
                                              void* __restrict__ Cout,
                                              int M, int N, int K, int ldc)
{
    __shared__ u16 As[128 * 40];
    __shared__ u16 Bs[64 * 40];

    const int tid  = threadIdx.x;
    const int w    = tid >> 6;
    const int lane = tid & 63;
    const int c    = lane & 15;
    const int quad = lane >> 4;
    const int m0   = blockIdx.y * 128;
    const int n0   = blockIdx.x * 64;

    const int rA = tid >> 2;            // 0..31
    const int kc = (tid & 3) << 3;      // 0,8,16,24

    const u16* Ap = A  + (size_t)(m0 + rA) * K + kc;
    const u16* Bp = Bt + (size_t)(n0 + rA) * K + kc;
    const size_t a32 = (size_t)32 * K;

    f32x4 acc[4][4];
#pragma unroll
    for (int i = 0; i < 4; i++)
#pragma unroll
        for (int j = 0; j < 4; j++) { acc[i][j][0]=0.f; acc[i][j][1]=0.f; acc[i][j][2]=0.f; acc[i][j][3]=0.f; }

    short8 ra[4], rb[2];
#pragma unroll
    for (int i = 0; i < 4; i++) ra[i] = *(const short8*)(Ap + i * a32);
#pragma unroll
    for (int i = 0; i < 2; i++) rb[i] = *(const short8*)(Bp + i * a32);

    for (int k0 = 0; k0 < K; k0 += 32) {
        __syncthreads();
#pragma unroll
        for (int i = 0; i < 4; i++) *(short8*)&As[(rA + i * 32) * 40 + kc] = ra[i];
#pragma unroll
        for (int i = 0; i < 2; i++) *(short8*)&Bs[(rA + i * 32) * 40 + kc] = rb[i];
        __syncthreads();

        if (k0 + 32 < K) {
#pragma unroll
            for (int i = 0; i < 4; i++) ra[i] = *(const short8*)(Ap + i * a32 + k0 + 32);
#pragma unroll
            for (int i = 0; i < 2; i++) rb[i] = *(const short8*)(Bp + i * a32 + k0 + 32);
        }

        short8 af[4], bf[4];
#pragma unroll
        for (int i = 0; i < 4; i++)
            af[i] = *(const short8*)&As[(w * 64 + i * 16 + c) * 40 + quad * 8];
#pragma unroll
        for (int j = 0; j < 4; j++)
            bf[j] = *(const short8*)&Bs[(j * 16 + c) * 40 + quad * 8];
#pragma unroll
        for (int i = 0; i < 4; i++)
#pragma unroll
            for (int j = 0; j < 4; j++)
                acc[i][j] = __builtin_amdgcn_mfma_f32_16x16x32_bf16(af[i], bf[j], acc[i][j], 0, 0, 0);
    }

    float bv[4];
#pragma unroll
    for (int j = 0; j < 4; j++) bv[j] = bias[n0 + j * 16 + c];

#pragma unroll
    for (int i = 0; i < 4; i++) {
#pragma unroll
        for (int j = 0; j < 4; j++) {
            int colg = n0 + j * 16 + c;
#pragma unroll
            for (int r = 0; r < 4; r++) {
                int rowg = m0 + w * 64 + i * 16 + quad * 4 + r;
                float v = acc[i][j][r] + bv[j];
                if (RELU) v = fmaxf(v, 0.f);
                if (OUT_BF16) ((u16*)Cout)[(size_t)rowg * ldc + colg] = f2bf(v);
                else          ((float*)Cout)[(size_t)rowg * ldc + colg] = v;
            }
        }
    }
}

// ---------------------------------------------------------------------------
// MFMA flash attention, v5: swapped QK^T -> P stays in registers.
//   Post-mortem v4: halving LDS reads/query LOST 9% with occupancy 21->12%
//   => latency-bound, not LDS-throughput-bound. The critical path was the
//   wave-local volatile P LDS round-trip (~120cy strictly-ordered) per tile.
//   v5 removes it structurally:
//   - QK^T computed SWAPPED: s[f] = mfma(A=K-frag, B=Q-frag). Register
//     contents of both frags identical to v3 (same LDS reads, same Q loads);
//     only operand order changes. Output S^T: col=lane&15=query,
//     row=quad*4+r=key. Each lane now holds P for ONE query (c) and keys
//     quad*4+r of each 16-key frag.
//   - PV A-operand built IN-REGISTER: 16x16x32 A has k-slot = quad*8+j;
//     with virtual key order s(slot): quad_s=slot>>3, j=slot&7,
//     key = (j<4 ? quad_s*4+j : 16+quad_s*4+(j-4)), the lane's 8 P values
//     (frag0 r=0..3, frag1 r=0..3) ARE the A-frag. No LDS, no shuffles.
//   - V^T staged in sigma order: Vt[dim][slot] = V[kt+key(slot)][dim];
//     gather baked into the (coalesced) 8-scalar V staging as before.
//     B-frag read = 8 consecutive u16 at row f2*16+c -> b128.
//   - Plds GONE (-8 LDS ops and the ordering stall per tile); denominator:
//     lane sums its 8 p's; epilogue: xor16+xor32 reduce -> D[query c],
//     rcp, then 4 dynamic shfl to fetch 1/D[quad*4+r] for the O rows.
//   - Double-buffered K/V LDS (19.5KB) -> ONE barrier per tile (write next
//     tile into buf^1 after computing from buf; barrier covers both RAW and
//     WAR). Register prefetch integral to the scheme.
//   Kept: v3 grid (32,32)=1024 blocks, 16 waves/CU TLP (v4 lesson), XCD
//   swizzle (FETCH 62->12MB), aligned strides 72/40 (16B rows), coalesced
//   staging.
// No max-subtraction (|s|<~2): unnormalized O += P*V, l += sum(exp) ==
// reference softmax; p=0 == exp(-1e9) underflow.
// Layouts (m89/m91): A[m=lane&15][k=quad*8+j], B[k=quad*8+j][n=lane&15],
// C/D: col=lane&15, row=quad*4+reg.
// ---------------------------------------------------------------------------
template<bool CAUSAL>
__global__ __launch_bounds__(256) void attn_mfma(const u16* __restrict__ Q,
                                                 const u16* __restrict__ K,
                                                 const u16* __restrict__ V,
                                                 u16* __restrict__ O,
                                                 int ldq, int ldk, int ldv)
{
    __shared__ u16 Klds[2][32 * 72];       // [buf][key][dim], 144B rows
    __shared__ u16 Vtlds[2][64 * 40];      // [buf][dim][sigma-slot], 80B rows

    const int tid  = threadIdx.x;
    const int w    = tid >> 6;
    const int lane = tid & 63;
    const int c    = lane & 15;
    const int quad = lane >> 4;

    // XCD-aware swizzle; grid is exactly (32, 32) = 1024 blocks = 8 XCDs * 128.
    const int flat = blockIdx.y * 32 + blockIdx.x;
    const int idx  = flat >> 3;
    const int bh   = (flat & 7) * 4 + (idx >> 5);   // 4 bh groups per XCD
    const int q0   = (idx & 31) * 64;

    const int b    = bh >> 3;
    const int h    = bh & 7;
    const int bS   = b * Sx;
    const int hoff = h * 64;
    const int qw   = q0 + w * 16;                // wave's first query

    // K staging: thread owns (key = tid>>3, dim chunk (tid&7)*8)
    const int kkey = tid >> 3;
    const int kc8  = (tid & 7) << 3;
    // V staging: thread owns (dim = tid&63, sigma-slots vp..vp+7)
    const int vdim = tid & 63;
    const int vq   = tid >> 6;                   // quad_s of owned slots
    const int vp   = vq << 3;
    // sigma key offsets for the 8 owned slots: j<4: vq*4+j ; j>=4: 16+vq*4+j-4
    int vkey[8];
#pragma unroll
    for (int j = 0; j < 8; j++) vkey[j] = ((j & 4) << 2) + (vq << 2) + (j & 3);

    short8 qa[2];
    {
        const u16* qp = Q + (size_t)(bS + qw + c) * ldq + hoff;
        qa[0] = *(const short8*)(qp + quad * 8);
        qa[1] = *(const short8*)(qp + 32 + quad * 8);
    }

    f32x4 of[4];
#pragma unroll
    for (int f = 0; f < 4; f++) { of[f][0]=0.f; of[f][1]=0.f; of[f][2]=0.f; of[f][3]=0.f; }
    float lpart = 0.f;

    const int kend = CAUSAL ? (q0 + 64) : Sx;

    // global staging pointers
    const u16* Kgp = K + (size_t)(bS + kkey) * ldk + hoff + kc8;
    const u16* Vgp = V + (size_t)bS * ldv + hoff + vdim;

    // ---- prologue: load + stage tile 0 ----
    {
        short8 kr = *(const short8*)(Kgp);
        union { short8 v; u16 u[8]; } vb;
#pragma unroll
        for (int j = 0; j < 8; j++) vb.u[j] = Vgp[(size_t)vkey[j] * ldv];
        *(short8*)&Klds[0][kkey * 72 + kc8] = kr;
        *(short8*)&Vtlds[0][vdim * 40 + vp] = vb.v;
    }
    __syncthreads();

    int cur = 0;
    for (int kt = 0; kt < kend; kt += 32) {
        const bool more = (kt + 32 < kend);

        // ---- prefetch next tile into registers (hidden under compute) ----
        short8 kr;
        union { short8 v; u16 u[8]; } vb;
        if (more) {
            kr = *(const short8*)(Kgp + (size_t)(kt + 32) * ldk);
#pragma unroll
            for (int j = 0; j < 8; j++)
                vb.u[j] = Vgp[(size_t)(kt + 32 + vkey[j]) * ldv];
        }

        int fm = 2;
        if (CAUSAL) {
            int d = ((qw + 15 - kt) >> 4) + 1;   // arithmetic shift: can be <=0
            fm = d < 2 ? d : 2;
        }

        if (fm > 0) {
            // ---- S^T = K Q^T for live key-frags (swapped operands) ----
            f32x4 s[2];
#pragma unroll
            for (int f = 0; f < 2; f++) {
                if (f < fm) {
                    short8 kb0 = *(const short8*)&Klds[cur][(f * 16 + c) * 72 + quad * 8];
                    short8 kb1 = *(const short8*)&Klds[cur][(f * 16 + c) * 72 + 32 + quad * 8];
                    f32x4 z; z[0]=0.f; z[1]=0.f; z[2]=0.f; z[3]=0.f;
                    z = __builtin_amdgcn_mfma_f32_16x16x32_bf16(kb0, qa[0], z, 0, 0, 0);
                    z = __builtin_amdgcn_mfma_f32_16x16x32_bf16(kb1, qa[1], z, 0, 0, 0);
                    s[f] = z;
                }
            }

            // ---- P = exp(S/8) in-lane; pack A-frag; accumulate denom ----
            const int qg = qw + c;               // this lane's query
            union { unsigned int u[4]; short8 s8; } pa;
#pragma unroll
            for (int f = 0; f < 2; f++) {
                u16 pb[4];
#pragma unroll
                for (int r = 0; r < 4; r++) {
                    float p = 0.f;
                    int kg = kt + f * 16 + quad * 4 + r;
                    if (f < fm && !(CAUSAL && kg > qg))
                        p = __expf(s[f][r] * 0.125f);
                    pb[r] = f2bf(p);
                    lpart += bf2f(pb[r]);
                }
                pa.u[f * 2 + 0] = (unsigned int)pb[0] | ((unsigned int)pb[1] << 16);
                pa.u[f * 2 + 1] = (unsigned int)pb[2] | ((unsigned int)pb[3] << 16);
            }

            // ---- O += P * V  (A in registers, B = sigma-ordered Vt) ----
#pragma unroll
            for (int f2 = 0; f2 < 4; f2++) {
                short8 vbf = *(const short8*)&Vtlds[cur][(f2 * 16 + c) * 40 + quad * 8];
                of[f2] = __builtin_amdgcn_mfma_f32_16x16x32_bf16(pa.s8, vbf, of[f2], 0, 0, 0);
            }
        }

        // ---- stage next tile into the other buffer ----
        if (more) {
            *(short8*)&Klds[cur ^ 1][kkey * 72 + kc8] = kr;
            *(short8*)&Vtlds[cur ^ 1][vdim * 40 + vp] = vb.v;
        }
        __syncthreads();                         // RAW(next) + WAR(cur) combined
        cur ^= 1;
    }

    // ---- denominators: D[query c] via xor16/32, then per-row fetch ----
    float D = lpart;
    D += __shfl_xor(D, 16, 64);
    D += __shfl_xor(D, 32, 64);
    float rcp = 1.f / D;                         // 1/D for query (qw + c)
    float rinv[4];
#pragma unroll
    for (int r = 0; r < 4; r++)
        rinv[r] = __shfl(rcp, quad * 4 + r, 64); // 1/D for query (qw+quad*4+r)

    // ---- write O (bf16, stride 512): row = quad*4+r, col = f*16+c ----
    u16* Ob = O + (size_t)(bS + qw) * Ex + hoff;
#pragma unroll
    for (int f = 0; f < 4; f++)
#pragma unroll
        for (int r = 0; r < 4; r++)
            Ob[(size_t)(quad * 4 + r) * Ex + f * 16 + c] = f2bf(of[f][r] * rinv[r]);
}

// ---------------------------------------------------------------------------
// Fused residual-add + LayerNorm over E=512; fp32 out + optional bf16 copy.
// ---------------------------------------------------------------------------
__global__ __launch_bounds__(256) void ln_add(const float* __restrict__ x,
                                              const float* __restrict__ s,
                                              const float* __restrict__ g,
                                              const float* __restrict__ bta,
                                              float* __restrict__ out,
                                              u16* __restrict__ out_bf)
{
    __shared__ float red[8];
    const int    row  = blockIdx.x;
    const int    t    = threadIdx.x;
    const size_t base = (size_t)row * Ex;

    float2 xv = *(const float2*)(x + base + (t << 1));
    float2 sv = *(const float2*)(s + base + (t << 1));
    float  y0 = xv.x + sv.x;
    float  y1 = xv.y + sv.y;

    float sum = y0 + y1;
    float sq  = y0 * y0 + y1 * y1;
#pragma unroll
    for (int o = 32; o > 0; o >>= 1) {
        sum += __shfl_down(sum, o, 64);
        sq  += __shfl_down(sq,  o, 64);
    }
    const int wid = t >> 6, lane = t & 63;
    if (lane == 0) { red[wid] = sum; red[4 + wid] = sq; }
    __syncthreads();
    if (t == 0) {
        red[0] = red[0] + red[1] + red[2] + red[3];
        red[4] = red[4] + red[5] + red[6] + red[7];
    }
    __syncthreads();

    const float mean = red[0] * (1.f / 512.f);
    const float var  = red[4] * (1.f / 512.f) - mean * mean;
    const float rstd = rsqrtf(var + 1e-3f);

    float2 gv = *(const float2*)(g   + (t << 1));
    float2 bv = *(const float2*)(bta + (t << 1));
    float  o0 = (y0 - mean) * rstd * gv.x + bv.x;
    float  o1 = (y1 - mean) * rstd * gv.y + bv.y;
    *(float2*)(out + base + (t << 1)) = make_float2(o0, o1);
    if (out_bf) {
        ushort2 ob; ob.x = f2bf(o0); ob.y = f2bf(o1);
        *(ushort2*)(out_bf + base + (t << 1)) = ob;
    }
}

// ---------------------------------------------------------------------------
// Orchestration. 96 MB workspace, byte offsets (MB):
//   [0,8)   bw: bf16 W^T x10 (8 square slots contiguous, then ff1, ff2)
//   [8,16)  xb     | P3: x2f = [8,24) fp32
//   [16,24) encb
//   [24,48) qkvB (stride 1536) | P2: qb=[24,32) str512, kvB=[32,48) str1024
//            | P3: ff1b = [24,56)
//   [48,56) ob (attn out, stride 512)
//   [56,72) projF fp32 (also ff2 out)
//   [72,88) x1f fp32
//   [88,96) x1b | P3: x2b
// ---------------------------------------------------------------------------
extern "C" void kernel_launch(void* const* d_in, const int* in_sizes, int n_in,
                              void* d_out, int out_size, void* d_ws, size_t ws_size,
                              hipStream_t stream)
{
    const float* x     = (const float*)d_in[0];
    const float* enc   = (const float*)d_in[1];
    const float* sa_Wq = (const float*)d_in[4],  *sa_bq = (const float*)d_in[5];
    const float* sa_Wk = (const float*)d_in[6],  *sa_bk = (const float*)d_in[7];
    const float* sa_Wv = (const float*)d_in[8],  *sa_bv = (const float*)d_in[9];
    const float* sa_Wo = (const float*)d_in[10], *sa_bo = (const float*)d_in[11];
    const float* ca_Wq = (const float*)d_in[12], *ca_bq = (const float*)d_in[13];
    const float* ca_Wk = (const float*)d_in[14], *ca_bk = (const float*)d_in[15];
    const float* ca_Wv = (const float*)d_in[16], *ca_bv = (const float*)d_in[17];
    const float* ca_Wo = (const float*)d_in[18], *ca_bo = (const float*)d_in[19];
    const float* ff_W1 = (const float*)d_in[20], *ff_b1 = (const float*)d_in[21];
    const float* ff_W2 = (const float*)d_in[22], *ff_b2 = (const float*)d_in[23];
    const float* ln1_g = (const float*)d_in[24], *ln1_b = (const float*)d_in[25];
    const float* ln2_g = (const float*)d_in[26], *ln2_b = (const float*)d_in[27];
    const float* ln3_g = (const float*)d_in[28], *ln3_b = (const float*)d_in[29];

    char* ws = (char*)d_ws;
    const size_t MB = 1024 * 1024;
    u16*   bw   = (u16*)(ws);
    u16*   xb   = (u16*)(ws + 8  * MB);
    u16*   encb = (u16*)(ws + 16 * MB);
    u16*   qkvB = (u16*)(ws + 24 * MB);
    u16*   qb   = (u16*)(ws + 24 * MB);
    u16*   kvB  = (u16*)(ws + 32 * MB);
    u16*   ff1b = (u16*)(ws + 24 * MB);
    u16*   ob   = (u16*)(ws + 48 * MB);
    float* projF= (float*)(ws + 56 * MB);
    float* x1f  = (float*)(ws + 72 * MB);
    u16*   x1b  = (u16*)(ws + 88 * MB);
    u16*   x2b  = (u16*)(ws + 88 * MB);
    float* x2f  = (float*)(ws + 8  * MB);

    // bf16 W^T slots: 8 squares contiguous (transpose8 order), then ff1/ff2
    u16* wsaq = bw;                 // QKV fused Bt = rows 0..1535 (q,k,v)
    u16* wsao = bw + 786432;
    u16* wcaq = bw + 1048576;
    u16* wcak = bw + 1310720;       // caKV fused Bt = rows 0..1023 (k,v)
    u16* wcao = bw + 1835008;
    u16* wff1 = bw + 2097152;
    u16* wff2 = bw + 3145728;

    // ---- pre-pass (4 launches) ----
    f32_to_bf16_2<<<dim3(Tt * Ex / 1024, 2), dim3(256), 0, stream>>>(x, enc, xb, encb);
    WPtrs wp; wp.w[0]=sa_Wq; wp.w[1]=sa_Wk; wp.w[2]=sa_Wv; wp.w[3]=sa_Wo;
    wp.w[4]=ca_Wq; wp.w[5]=ca_Wk; wp.w[6]=ca_Wv; wp.w[7]=ca_Wo;
    transpose8_bf16<<<dim3(16, 16, 8), dim3(256), 0, stream>>>(wp, bw);
    transpose_bf16<<<dim3(64, 16), dim3(256), 0, stream>>>(ff_W1, wff1, 512, 2048);
    transpose_bf16<<<dim3(16, 64), dim3(256), 0, stream>>>(ff_W2, wff2, 2048, 512);

    auto G128 = [&](const u16* A, const u16* Wt, const float* b0, const float* b1,
                    const float* b2, const float* b3, void* C,
                    int N, int K, int ldc, int out_bf, int relu) {
        dim3 grid(N / 128, Tt / 128);
        if (out_bf) {
            if (relu) gemm128<1,1><<<grid, dim3(256), 0, stream>>>(A, Wt, b0,b1,b2,b3, C, Tt, N, K, ldc);
            else      gemm128<1,0><<<grid, dim3(256), 0, stream>>>(A, Wt, b0,b1,b2,b3, C, Tt, N, K, ldc);
        } else        gemm128<0,0><<<grid, dim3(256), 0, stream>>>(A, Wt, b0,b1,b2,b3, C, Tt, N, K, ldc);
    };
    auto G64 = [&](const u16* A, const u16* Wt, const float* bi, void* C,
                   int K, int ldc, int out_bf) {
        dim3 grid(512 / 64, Tt / 128);
        if (out_bf) gemm64<1,0><<<grid, dim3(128), 0, stream>>>(A, Wt, bi, C, Tt, 512, K, ldc);
        else        gemm64<0,0><<<grid, dim3(128), 0, stream>>>(A, Wt, bi, C, Tt, 512, K, ldc);
    };
    const dim3 agrid(Sx / 64, Bx * Hx);     // (32, 32)

    // ---- stage 1: fused QKV GEMM + self-attn + add&norm ----
    G128(xb, wsaq, sa_bq, sa_bk, sa_bv, sa_bv, qkvB, 1536, 512, 1536, 1, 0);
    attn_mfma<true><<<agrid, dim3(256), 0, stream>>>(qkvB, qkvB + 512, qkvB + 1024,
                                                     ob, 1536, 1536, 1536);
    G64(ob, wsao, sa_bo, projF, 512, 512, 0);
    ln_add<<<dim3(Tt), dim3(256), 0, stream>>>(x, projF, ln1_g, ln1_b, x1f, x1b);

    // ---- stage 2: cross-attention + add&norm ----
    G64(x1b, wcaq, ca_bq, qb, 512, 512, 1);
    G128(encb, wcak, ca_bk, ca_bv, ca_bv, ca_bv, kvB, 1024, 512, 1024, 1, 0);
    attn_mfma<false><<<agrid, dim3(256), 0, stream>>>(qb, kvB, kvB + 512,
                                                      ob, 512, 1024, 1024);
    G64(ob, wcao, ca_bo, projF, 512, 512, 0);
    ln_add<<<dim3(Tt), dim3(256), 0, stream>>>(x1f, projF, ln2_g, ln2_b, x2f, x2b);

    // ---- stage 3: FFN + add&norm ----
    G128(x2b, wff1, ff_b1, ff_b1 + 512, ff_b1 + 1024, ff_b1 + 1536,
         ff1b, 2048, 512, 2048, 1, 1);                       // ReLU
    G64(ff1b, wff2, ff_b2, projF, 2048, 512, 0);
    ln_add<<<dim3(Tt), dim3(256), 0, stream>>>(x2f, projF, ln3_g, ln3_b,
                                               (float*)d_out, (u16*)nullptr);
}

// Round 5
// 495.178 us; speedup vs baseline: 1.1496x; 1.0246x over previous
//
#include <hip/hip_runtime.h>

// Problem constants (B,S,E,H,DK,DV,DF) = (4,2048,512,8,64,64,2048)
#define Bx  4
#define Sx  2048
#define Ex  512
#define Hx  8
#define Tt  (Bx * Sx)          // 8192 tokens

typedef short          short8 __attribute__((ext_vector_type(8)));  // 8 bf16
typedef float          f32x4  __attribute__((ext_vector_type(4)));  // MFMA C/D
typedef unsigned short u16;

__device__ __forceinline__ u16 f2bf(float f) {
    unsigned int u = __float_as_uint(f);
    u += 0x7fffu + ((u >> 16) & 1u);          // round-to-nearest-even
    return (u16)(u >> 16);
}
__device__ __forceinline__ float bf2f(u16 h) {
    return __uint_as_float(((unsigned int)h) << 16);
}

// ---------------------------------------------------------------------------
// fp32 -> bf16 flat convert, two tensors in one dispatch (grid.y selects).
// ---------------------------------------------------------------------------
__global__ __launch_bounds__(256) void f32_to_bf16_2(const float* __restrict__ a,
                                                     const float* __restrict__ b,
                                                     u16* __restrict__ oa,
                                                     u16* __restrict__ ob)
{
    const float* in  = blockIdx.y ? b : a;
    u16*         out = blockIdx.y ? ob : oa;
    int i = (blockIdx.x * 256 + threadIdx.x) << 2;
    float4 v = *(const float4*)(in + i);
    ushort4 o;
    o.x = f2bf(v.x); o.y = f2bf(v.y); o.z = f2bf(v.z); o.w = f2bf(v.w);
    *(ushort4*)(out + i) = o;
}

// ---------------------------------------------------------------------------
// W (K x N fp32) -> Wt (N x K bf16). Generic (for ff_W1/ff_W2).
// ---------------------------------------------------------------------------
__global__ __launch_bounds__(256) void transpose_bf16(const float* __restrict__ W,
                                                      u16* __restrict__ Wt,
                                                      int K, int N)
{
    __shared__ u16 tile[32][33];
    const int n0 = blockIdx.x * 32, k0 = blockIdx.y * 32;
    const int tx = threadIdx.x & 31, ty = threadIdx.x >> 5;   // ty 0..7
#pragma unroll
    for (int i = 0; i < 32; i += 8)
        tile[ty + i][tx] = f2bf(W[(size_t)(k0 + ty + i) * N + n0 + tx]);
    __syncthreads();
#pragma unroll
    for (int i = 0; i < 32; i += 8)
        Wt[(size_t)(n0 + ty + i) * K + k0 + tx] = tile[tx][ty + i];
}

// ---------------------------------------------------------------------------
// 8x 512x512 transposes in one dispatch; slot z writes base + z*262144.
// ---------------------------------------------------------------------------
struct WPtrs { const float* w[8]; };
__global__ __launch_bounds__(256) void transpose8_bf16(WPtrs ws, u16* __restrict__ base)
{
    __shared__ u16 tile[32][33];
    const float* W  = ws.w[blockIdx.z];
    u16*         Wt = base + (size_t)blockIdx.z * 262144;
    const int n0 = blockIdx.x * 32, k0 = blockIdx.y * 32;
    const int tx = threadIdx.x & 31, ty = threadIdx.x >> 5;
#pragma unroll
    for (int i = 0; i < 32; i += 8)
        tile[ty + i][tx] = f2bf(W[(size_t)(k0 + ty + i) * 512 + n0 + tx]);
    __syncthreads();
#pragma unroll
    for (int i = 0; i < 32; i += 8)
        Wt[(size_t)(n0 + ty + i) * 512 + k0 + tx] = tile[tx][ty + i];
}

// ---------------------------------------------------------------------------
// gemm128: 128x128 tile, BK=32, 256 thr = 4 waves (2x2), wave 64x64.
// ---------------------------------------------------------------------------
template<int OUT_BF16, int RELU>
__global__ __launch_bounds__(256) void gemm128(const u16* __restrict__ A,
                                               const u16* __restrict__ Bt,
                                               const float* __restrict__ b0,
                                               const float* __restrict__ b1,
                                               const float* __restrict__ b2,
                                               const float* __restrict__ b3,
                                               void* __restrict__ Cout,
                                               int M, int N, int K, int ldc)
{
    __shared__ u16 As[128 * 40];
    __shared__ u16 Bs[128 * 40];

    const int tid  = threadIdx.x;
    const int w    = tid >> 6;
    const int lane = tid & 63;
    const int c    = lane & 15;
    const int quad = lane >> 4;
    const int wr   = w >> 1, wc = w & 1;
    const int m0   = blockIdx.y * 128;
    const int n0   = blockIdx.x * 128;

    const int row0 = tid >> 2;           // 0..63
    const int kc   = (tid & 3) << 3;     // 0,8,16,24

    const u16* Ap = A  + (size_t)(m0 + row0) * K + kc;
    const u16* Bp = Bt + (size_t)(n0 + row0) * K + kc;
    const size_t rstep = (size_t)64 * K;

    f32x4 acc[4][4];
#pragma unroll
    for (int i = 0; i < 4; i++)
#pragma unroll
        for (int j = 0; j < 4; j++) { acc[i][j][0]=0.f; acc[i][j][1]=0.f; acc[i][j][2]=0.f; acc[i][j][3]=0.f; }

    short8 ra0 = *(const short8*)(Ap);
    short8 ra1 = *(const short8*)(Ap + rstep);
    short8 rb0 = *(const short8*)(Bp);
    short8 rb1 = *(const short8*)(Bp + rstep);

    for (int k0 = 0; k0 < K; k0 += 32) {
        __syncthreads();
        *(short8*)&As[row0 * 40 + kc]        = ra0;
        *(short8*)&As[(row0 + 64) * 40 + kc] = ra1;
        *(short8*)&Bs[row0 * 40 + kc]        = rb0;
        *(short8*)&Bs[(row0 + 64) * 40 + kc] = rb1;
        __syncthreads();

        if (k0 + 32 < K) {
            ra0 = *(const short8*)(Ap + k0 + 32);
            ra1 = *(const short8*)(Ap + rstep + k0 + 32);
            rb0 = *(const short8*)(Bp + k0 + 32);
            rb1 = *(const short8*)(Bp + rstep + k0 + 32);
        }

        short8 af[4], bf[4];
#pragma unroll
        for (int i = 0; i < 4; i++)
            af[i] = *(const short8*)&As[(wr * 64 + i * 16 + c) * 40 + quad * 8];
#pragma unroll
        for (int j = 0; j < 4; j++)
            bf[j] = *(const short8*)&Bs[(wc * 64 + j * 16 + c) * 40 + quad * 8];
#pragma unroll
        for (int i = 0; i < 4; i++)
#pragma unroll
            for (int j = 0; j < 4; j++)
                acc[i][j] = __builtin_amdgcn_mfma_f32_16x16x32_bf16(af[i], bf[j], acc[i][j], 0, 0, 0);
    }

    // ---- epilogue ----
    const int seg = n0 >> 9;
    const float* bp = seg == 0 ? b0 : (seg == 1 ? b1 : (seg == 2 ? b2 : b3));
    const int nbase = n0 & 511;
    float bv[4];
#pragma unroll
    for (int j = 0; j < 4; j++) bv[j] = bp[nbase + wc * 64 + j * 16 + c];

#pragma unroll
    for (int i = 0; i < 4; i++) {
#pragma unroll
        for (int j = 0; j < 4; j++) {
            int colg = n0 + wc * 64 + j * 16 + c;
#pragma unroll
            for (int r = 0; r < 4; r++) {
                int rowg = m0 + wr * 64 + i * 16 + quad * 4 + r;
                float v = acc[i][j][r] + bv[j];
                if (RELU) v = fmaxf(v, 0.f);
                if (OUT_BF16) ((u16*)Cout)[(size_t)rowg * ldc + colg] = f2bf(v);
                else          ((float*)Cout)[(size_t)rowg * ldc + colg] = v;
            }
        }
    }
}

// ---------------------------------------------------------------------------
// gemm64: 128x64 tile, BK=32, 128 thr = 2 waves.
// ---------------------------------------------------------------------------
template<int OUT_BF16, int RELU>
__global__ __launch_bounds__(128) void gemm64(const u16* __restrict__ A,
                                              const u16* __restrict__ Bt,
                                              const float* __restrict__ bias,
                                              void* __restrict__ Cout,
                                              int M, int N, int K, int ldc)
{
    __shared__ u16 As[128 * 40];
    __shared__ u16 Bs[64 * 40];

    const int tid  = threadIdx.x;
    const int w    = tid >> 6;
    const int lane = tid & 63;
    const int c    = lane & 15;
    const int quad = lane >> 4;
    const int m0   = blockIdx.y * 128;
    const int n0   = blockIdx.x * 64;

    const int rA = tid >> 2;            // 0..31
    const int kc = (tid & 3) << 3;      // 0,8,16,24

    const u16* Ap = A  + (size_t)(m0 + rA) * K + kc;
    const u16* Bp = Bt + (size_t)(n0 + rA) * K + kc;
    const size_t a32 = (size_t)32 * K;

    f32x4 acc[4][4];
#pragma unroll
    for (int i = 0; i < 4; i++)
#pragma unroll
        for (int j = 0; j < 4; j++) { acc[i][j][0]=0.f; acc[i][j][1]=0.f; acc[i][j][2]=0.f; acc[i][j][3]=0.f; }

    short8 ra[4], rb[2];
#pragma unroll
    for (int i = 0; i < 4; i++) ra[i] = *(const short8*)(Ap + i * a32);
#pragma unroll
    for (int i = 0; i < 2; i++) rb[i] = *(const short8*)(Bp + i * a32);

    for (int k0 = 0; k0 < K; k0 += 32) {
        __syncthreads();
#pragma unroll
        for (int i = 0; i < 4; i++) *(short8*)&As[(rA + i * 32) * 40 + kc] = ra[i];
#pragma unroll
        for (int i = 0; i < 2; i++) *(short8*)&Bs[(rA + i * 32) * 40 + kc] = rb[i];
        __syncthreads();

        if (k0 + 32 < K) {
#pragma unroll
            for (int i = 0; i < 4; i++) ra[i] = *(const short8*)(Ap + i * a32 + k0 + 32);
#pragma unroll
            for (int i = 0; i < 2; i++) rb[i] = *(const short8*)(Bp + i * a32 + k0 + 32);
        }

        short8 af[4], bf[4];
#pragma unroll
        for (int i = 0; i < 4; i++)
            af[i] = *(const short8*)&As[(w * 64 + i * 16 + c) * 40 + quad * 8];
#pragma unroll
        for (int j = 0; j < 4; j++)
            bf[j] = *(const short8*)&Bs[(j * 16 + c) * 40 + quad * 8];
#pragma unroll
        for (int i = 0; i < 4; i++)
#pragma unroll
            for (int j = 0; j < 4; j++)
                acc[i][j] = __builtin_amdgcn_mfma_f32_16x16x32_bf16(af[i], bf[j], acc[i][j], 0, 0, 0);
    }

    float bv[4];
#pragma unroll
    for (int j = 0; j < 4; j++) bv[j] = bias[n0 + j * 16 + c];

#pragma unroll
    for (int i = 0; i < 4; i++) {
#pragma unroll
        for (int j = 0; j < 4; j++) {
            int colg = n0 + j * 16 + c;
#pragma unroll
            for (int r = 0; r < 4; r++) {
                int rowg = m0 + w * 64 + i * 16 + quad * 4 + r;
                float v = acc[i][j][r] + bv[j];
                if (RELU) v = fmaxf(v, 0.f);
                if (OUT_BF16) ((u16*)Cout)[(size_t)rowg * ldc + colg] = f2bf(v);
                else          ((float*)Cout)[(size_t)rowg * ldc + colg] = v;
            }
        }
    }
}

// ---------------------------------------------------------------------------
// MFMA flash attention, v6: v5's in-register P + 32 q/wave + KVBLK=64.
//   Post-mortem v5 (98.7us): per-CU LDS b128 traffic ~52% busy, VALU 38%,
//   MFMA 17% -- no pipe saturated, poor overlap, all 4 waves read identical
//   K/V tiles from LDS. v6:
//   - 2 Q-frags per wave (32 q). In swapped-QK mode Q is the MFMA *B*
//     operand, so the second Q-frag reuses the SAME kb/vb LDS reads ->
//     per-CU LDS read traffic per query halves. Exp/VALU per query same.
//   - KVBLK=64, double-buffered (Klds/Vt [2][64][72], 36.9KB): ONE barrier
//     per 64 keys (v5: two) and 32 MFMA per wave between barriers -> pipes
//     overlap across a longer phase; fixed costs per key quartered.
//   - v4's 8-wave trap does not apply: no serialized P LDS round-trip;
//     ILP doubled (2 independent S chains, 8 PV chains).
//   Grid (16,32)=512 blocks = 2/CU = 8 waves/CU; XCD swizzle bijective:
//   8 XCDs x 4 bh-groups x 16 q-tiles. Staging: K 2 b128/thread; V 16
//   coalesced ushort gathers -> 2 b128 writes (sigma baked in).
//   Causal: per (wave, q-frag) live-frag counts fm0/fm1 (fm1>=fm0); PV
//   halves guarded (fm>2) to skip dead key-halves on diagonal tiles.
// No max-subtraction (|s|<~2): unnormalized O += P*V, l += sum(exp) ==
// reference softmax; p=0 == exp(-1e9) underflow.
// Layouts (m89/m91): A[m=lane&15][k=quad*8+j], B[k=quad*8+j][n=lane&15],
// C/D: col=lane&15, row=quad*4+reg. sigma(slot): qs=slot>>3, j=slot&7,
// key = (j<4 ? qs*4+j : 16+qs*4+j-4); applied identically to P-pack (A) and
// V^T staging (B) so it cancels under contraction.
// ---------------------------------------------------------------------------
template<bool CAUSAL>
__global__ __launch_bounds__(256) void attn_mfma(const u16* __restrict__ Q,
                                                 const u16* __restrict__ K,
                                                 const u16* __restrict__ V,
                                                 u16* __restrict__ O,
                                                 int ldq, int ldk, int ldv)
{
    __shared__ u16 Klds[2][64 * 72];       // [buf][key][dim], 144B rows
    __shared__ u16 Vtlds[2][64 * 72];      // [buf][dim][sigma-slot 0..63]

    const int tid  = threadIdx.x;
    const int w    = tid >> 6;
    const int lane = tid & 63;
    const int c    = lane & 15;
    const int quad = lane >> 4;

    // XCD-aware swizzle; grid (16, 32) = 512 blocks = 8 XCDs * 64.
    const int flat = blockIdx.y * 16 + blockIdx.x;
    const int idx  = flat >> 3;                     // 0..63 within XCD
    const int bh   = (flat & 7) * 4 + (idx >> 4);   // 4 bh groups per XCD
    const int q0   = (idx & 15) * 128;

    const int b    = bh >> 3;
    const int h    = bh & 7;
    const int bS   = b * Sx;
    const int hoff = h * 64;
    const int qw   = q0 + w * 32;                // wave's first query (32/wave)

    // K staging: thread owns keys (tid>>3, +32), dim chunk (tid&7)*8
    const int kkey = tid >> 3;
    const int kc8  = (tid & 7) << 3;
    // V staging: thread owns dim tid&63, sigma-slots vp..vp+7 (+32)
    const int vdim = tid & 63;
    const int vq   = tid >> 6;
    const int vp   = vq << 3;
    int vkey[8];
#pragma unroll
    for (int j = 0; j < 8; j++) vkey[j] = ((j & 4) << 2) + (vq << 2) + (j & 3);

    short8 qa[2][2];                             // [q-frag][k-half]
#pragma unroll
    for (int a = 0; a < 2; a++) {
        const u16* qp = Q + (size_t)(bS + qw + a * 16 + c) * ldq + hoff;
        qa[a][0] = *(const short8*)(qp + quad * 8);
        qa[a][1] = *(const short8*)(qp + 32 + quad * 8);
    }

    f32x4 of[2][4];
#pragma unroll
    for (int a = 0; a < 2; a++)
#pragma unroll
        for (int f = 0; f < 4; f++) { of[a][f][0]=0.f; of[a][f][1]=0.f; of[a][f][2]=0.f; of[a][f][3]=0.f; }
    float lpart[2] = {0.f, 0.f};

    const int kend = CAUSAL ? (q0 + 128) : Sx;

    const u16* Kgp = K + (size_t)(bS + kkey) * ldk + hoff + kc8;
    const u16* Vgp = V + (size_t)bS * ldv + hoff + vdim;
    const size_t k32 = (size_t)32 * ldk;

    // ---- prologue: load + stage tile 0 ----
    {
        short8 kr0 = *(const short8*)(Kgp);
        short8 kr1 = *(const short8*)(Kgp + k32);
        union { short8 v; u16 u[8]; } vb0, vb1;
#pragma unroll
        for (int j = 0; j < 8; j++) vb0.u[j] = Vgp[(size_t)vkey[j] * ldv];
#pragma unroll
        for (int j = 0; j < 8; j++) vb1.u[j] = Vgp[(size_t)(32 + vkey[j]) * ldv];
        *(short8*)&Klds[0][kkey * 72 + kc8]        = kr0;
        *(short8*)&Klds[0][(kkey + 32) * 72 + kc8] = kr1;
        *(short8*)&Vtlds[0][vdim * 72 + vp]        = vb0.v;
        *(short8*)&Vtlds[0][vdim * 72 + 32 + vp]   = vb1.v;
    }
    __syncthreads();

    int cur = 0;
    for (int kt = 0; kt < kend; kt += 64) {
        const bool more = (kt + 64 < kend);

        // ---- prefetch next tile into registers (hidden under compute) ----
        short8 kr0, kr1;
        union { short8 v; u16 u[8]; } vb0, vb1;
        if (more) {
            const u16* kp = Kgp + (size_t)(kt + 64) * ldk;
            kr0 = *(const short8*)(kp);
            kr1 = *(const short8*)(kp + k32);
#pragma unroll
            for (int j = 0; j < 8; j++)
                vb0.u[j] = Vgp[(size_t)(kt + 64 + vkey[j]) * ldv];
#pragma unroll
            for (int j = 0; j < 8; j++)
                vb1.u[j] = Vgp[(size_t)(kt + 96 + vkey[j]) * ldv];
        }

        int fm0 = 4, fm1 = 4;                    // live 16-key frags per q-frag
        if (CAUSAL) {
            int d0 = ((qw + 15 - kt) >> 4) + 1;  // arithmetic shift: can be <=0
            int d1 = ((qw + 31 - kt) >> 4) + 1;
            fm0 = d0 < 0 ? 0 : (d0 > 4 ? 4 : d0);
            fm1 = d1 < 0 ? 0 : (d1 > 4 ? 4 : d1);   // fm1 >= fm0
        }

        if (fm1 > 0) {
            // ---- S^T = K Q^T; kb reads shared across both q-frags ----
            f32x4 s[2][4];
#pragma unroll
            for (int f = 0; f < 4; f++) {
                if (f < fm1) {
                    short8 kb0 = *(const short8*)&Klds[cur][(f * 16 + c) * 72 + quad * 8];
                    short8 kb1 = *(const short8*)&Klds[cur][(f * 16 + c) * 72 + 32 + quad * 8];
#pragma unroll
                    for (int a = 0; a < 2; a++) {
                        const int fma_ = a ? fm1 : fm0;
                        if (f < fma_) {
                            f32x4 z; z[0]=0.f; z[1]=0.f; z[2]=0.f; z[3]=0.f;
                            z = __builtin_amdgcn_mfma_f32_16x16x32_bf16(kb0, qa[a][0], z, 0, 0, 0);
                            z = __builtin_amdgcn_mfma_f32_16x16x32_bf16(kb1, qa[a][1], z, 0, 0, 0);
                            s[a][f] = z;
                        }
                    }
                }
            }

            // ---- P = exp(S/8) in-lane; pack A-frags; accumulate denom ----
            union { unsigned int u[4]; short8 s8; } paA[2], paB[2];
#pragma unroll
            for (int a = 0; a < 2; a++) {
                const int fma_ = a ? fm1 : fm0;
                const int qg = qw + a * 16 + c;  // this lane's query
#pragma unroll
                for (int f = 0; f < 4; f++) {
                    u16 pb[4];
#pragma unroll
                    for (int r = 0; r < 4; r++) {
                        float p = 0.f;
                        int kg = kt + f * 16 + quad * 4 + r;
                        if (f < fma_ && !(CAUSAL && kg > qg))
                            p = __expf(s[a][f][r] * 0.125f);
                        pb[r] = f2bf(p);
                        lpart[a] += bf2f(pb[r]);
                    }
                    unsigned int w0 = (unsigned int)pb[0] | ((unsigned int)pb[1] << 16);
                    unsigned int w1 = (unsigned int)pb[2] | ((unsigned int)pb[3] << 16);
                    if (f < 2) { paA[a].u[f * 2] = w0; paA[a].u[f * 2 + 1] = w1; }
                    else       { paB[a].u[(f - 2) * 2] = w0; paB[a].u[(f - 2) * 2 + 1] = w1; }
                }
            }

            // ---- O += P * V; vb reads shared across both q-frags ----
#pragma unroll
            for (int f2 = 0; f2 < 4; f2++) {
                short8 vb0f = *(const short8*)&Vtlds[cur][(f2 * 16 + c) * 72 + quad * 8];
                short8 vb1f = *(const short8*)&Vtlds[cur][(f2 * 16 + c) * 72 + 32 + quad * 8];
                if (fm0 > 0)
                    of[0][f2] = __builtin_amdgcn_mfma_f32_16x16x32_bf16(paA[0].s8, vb0f, of[0][f2], 0, 0, 0);
                of[1][f2] = __builtin_amdgcn_mfma_f32_16x16x32_bf16(paA[1].s8, vb0f, of[1][f2], 0, 0, 0);
                if (fm0 > 2)
                    of[0][f2] = __builtin_amdgcn_mfma_f32_16x16x32_bf16(paB[0].s8, vb1f, of[0][f2], 0, 0, 0);
                if (fm1 > 2)
                    of[1][f2] = __builtin_amdgcn_mfma_f32_16x16x32_bf16(paB[1].s8, vb1f, of[1][f2], 0, 0, 0);
            }
        }

        // ---- stage next tile into the other buffer ----
        if (more) {
            *(short8*)&Klds[cur ^ 1][kkey * 72 + kc8]        = kr0;
            *(short8*)&Klds[cur ^ 1][(kkey + 32) * 72 + kc8] = kr1;
            *(short8*)&Vtlds[cur ^ 1][vdim * 72 + vp]        = vb0.v;
            *(short8*)&Vtlds[cur ^ 1][vdim * 72 + 32 + vp]   = vb1.v;
        }
        __syncthreads();                         // RAW(next) + WAR(cur)
        cur ^= 1;
    }

    // ---- denominators: D[query] via xor16/32, then per-row fetch ----
    float rinv[2][4];
#pragma unroll
    for (int a = 0; a < 2; a++) {
        float D = lpart[a];
        D += __shfl_xor(D, 16, 64);
        D += __shfl_xor(D, 32, 64);
        float rcp = 1.f / D;                     // 1/D for query (qw+a*16+c)
#pragma unroll
        for (int r = 0; r < 4; r++)
            rinv[a][r] = __shfl(rcp, quad * 4 + r, 64);
    }

    // ---- write O (bf16, stride 512): row = a*16+quad*4+r, col = f*16+c ----
    u16* Ob = O + (size_t)(bS + qw) * Ex + hoff;
#pragma unroll
    for (int a = 0; a < 2; a++)
#pragma unroll
        for (int f = 0; f < 4; f++)
#pragma unroll
            for (int r = 0; r < 4; r++)
                Ob[(size_t)(a * 16 + quad * 4 + r) * Ex + f * 16 + c] =
                    f2bf(of[a][f][r] * rinv[a][r]);
}

// ---------------------------------------------------------------------------
// Fused residual-add + LayerNorm over E=512; fp32 out + optional bf16 copy.
// ---------------------------------------------------------------------------
__global__ __launch_bounds__(256) void ln_add(const float* __restrict__ x,
                                              const float* __restrict__ s,
                                              const float* __restrict__ g,
                                              const float* __restrict__ bta,
                                              float* __restrict__ out,
                                              u16* __restrict__ out_bf)
{
    __shared__ float red[8];
    const int    row  = blockIdx.x;
    const int    t    = threadIdx.x;
    const size_t base = (size_t)row * Ex;

    float2 xv = *(const float2*)(x + base + (t << 1));
    float2 sv = *(const float2*)(s + base + (t << 1));
    float  y0 = xv.x + sv.x;
    float  y1 = xv.y + sv.y;

    float sum = y0 + y1;
    float sq  = y0 * y0 + y1 * y1;
#pragma unroll
    for (int o = 32; o > 0; o >>= 1) {
        sum += __shfl_down(sum, o, 64);
        sq  += __shfl_down(sq,  o, 64);
    }
    const int wid = t >> 6, lane = t & 63;
    if (lane == 0) { red[wid] = sum; red[4 + wid] = sq; }
    __syncthreads();
    if (t == 0) {
        red[0] = red[0] + red[1] + red[2] + red[3];
        red[4] = red[4] + red[5] + red[6] + red[7];
    }
    __syncthreads();

    const float mean = red[0] * (1.f / 512.f);
    const float var  = red[4] * (1.f / 512.f) - mean * mean;
    const float rstd = rsqrtf(var + 1e-3f);

    float2 gv = *(const float2*)(g   + (t << 1));
    float2 bv = *(const float2*)(bta + (t << 1));
    float  o0 = (y0 - mean) * rstd * gv.x + bv.x;
    float  o1 = (y1 - mean) * rstd * gv.y + bv.y;
    *(float2*)(out + base + (t << 1)) = make_float2(o0, o1);
    if (out_bf) {
        ushort2 ob; ob.x = f2bf(o0); ob.y = f2bf(o1);
        *(ushort2*)(out_bf + base + (t << 1)) = ob;
    }
}

// ---------------------------------------------------------------------------
// Orchestration. 96 MB workspace, byte offsets (MB):
//   [0,8)   bw: bf16 W^T x10 (8 square slots contiguous, then ff1, ff2)
//   [8,16)  xb     | P3: x2f = [8,24) fp32
//   [16,24) encb
//   [24,48) qkvB (stride 1536) | P2: qb=[24,32) str512, kvB=[32,48) str1024
//            | P3: ff1b = [24,56)
//   [48,56) ob (attn out, stride 512)
//   [56,72) projF fp32 (also ff2 out)
//   [72,88) x1f fp32
//   [88,96) x1b | P3: x2b
// ---------------------------------------------------------------------------
extern "C" void kernel_launch(void* const* d_in, const int* in_sizes, int n_in,
                              void* d_out, int out_size, void* d_ws, size_t ws_size,
                              hipStream_t stream)
{
    const float* x     = (const float*)d_in[0];
    const float* enc   = (const float*)d_in[1];
    const float* sa_Wq = (const float*)d_in[4],  *sa_bq = (const float*)d_in[5];
    const float* sa_Wk = (const float*)d_in[6],  *sa_bk = (const float*)d_in[7];
    const float* sa_Wv = (const float*)d_in[8],  *sa_bv = (const float*)d_in[9];
    const float* sa_Wo = (const float*)d_in[10], *sa_bo = (const float*)d_in[11];
    const float* ca_Wq = (const float*)d_in[12], *ca_bq = (const float*)d_in[13];
    const float* ca_Wk = (const float*)d_in[14], *ca_bk = (const float*)d_in[15];
    const float* ca_Wv = (const float*)d_in[16], *ca_bv = (const float*)d_in[17];
    const float* ca_Wo = (const float*)d_in[18], *ca_bo = (const float*)d_in[19];
    const float* ff_W1 = (const float*)d_in[20], *ff_b1 = (const float*)d_in[21];
    const float* ff_W2 = (const float*)d_in[22], *ff_b2 = (const float*)d_in[23];
    const float* ln1_g = (const float*)d_in[24], *ln1_b = (const float*)d_in[25];
    const float* ln2_g = (const float*)d_in[26], *ln2_b = (const float*)d_in[27];
    const float* ln3_g = (const float*)d_in[28], *ln3_b = (const float*)d_in[29];

    char* ws = (char*)d_ws;
    const size_t MB = 1024 * 1024;
    u16*   bw   = (u16*)(ws);
    u16*   xb   = (u16*)(ws + 8  * MB);
    u16*   encb = (u16*)(ws + 16 * MB);
    u16*   qkvB = (u16*)(ws + 24 * MB);
    u16*   qb   = (u16*)(ws + 24 * MB);
    u16*   kvB  = (u16*)(ws + 32 * MB);
    u16*   ff1b = (u16*)(ws + 24 * MB);
    u16*   ob   = (u16*)(ws + 48 * MB);
    float* projF= (float*)(ws + 56 * MB);
    float* x1f  = (float*)(ws + 72 * MB);
    u16*   x1b  = (u16*)(ws + 88 * MB);
    u16*   x2b  = (u16*)(ws + 88 * MB);
    float* x2f  = (float*)(ws + 8  * MB);

    // bf16 W^T slots: 8 squares contiguous (transpose8 order), then ff1/ff2
    u16* wsaq = bw;                 // QKV fused Bt = rows 0..1535 (q,k,v)
    u16* wsao = bw + 786432;
    u16* wcaq = bw + 1048576;
    u16* wcak = bw + 1310720;       // caKV fused Bt = rows 0..1023 (k,v)
    u16* wcao = bw + 1835008;
    u16* wff1 = bw + 2097152;
    u16* wff2 = bw + 3145728;

    // ---- pre-pass (4 launches) ----
    f32_to_bf16_2<<<dim3(Tt * Ex / 1024, 2), dim3(256), 0, stream>>>(x, enc, xb, encb);
    WPtrs wp; wp.w[0]=sa_Wq; wp.w[1]=sa_Wk; wp.w[2]=sa_Wv; wp.w[3]=sa_Wo;
    wp.w[4]=ca_Wq; wp.w[5]=ca_Wk; wp.w[6]=ca_Wv; wp.w[7]=ca_Wo;
    transpose8_bf16<<<dim3(16, 16, 8), dim3(256), 0, stream>>>(wp, bw);
    transpose_bf16<<<dim3(64, 16), dim3(256), 0, stream>>>(ff_W1, wff1, 512, 2048);
    transpose_bf16<<<dim3(16, 64), dim3(256), 0, stream>>>(ff_W2, wff2, 2048, 512);

    auto G128 = [&](const u16* A, const u16* Wt, const float* b0, const float* b1,
                    const float* b2, const float* b3, void* C,
                    int N, int K, int ldc, int out_bf, int relu) {
        dim3 grid(N / 128, Tt / 128);
        if (out_bf) {
            if (relu) gemm128<1,1><<<grid, dim3(256), 0, stream>>>(A, Wt, b0,b1,b2,b3, C, Tt, N, K, ldc);
            else      gemm128<1,0><<<grid, dim3(256), 0, stream>>>(A, Wt, b0,b1,b2,b3, C, Tt, N, K, ldc);
        } else        gemm128<0,0><<<grid, dim3(256), 0, stream>>>(A, Wt, b0,b1,b2,b3, C, Tt, N, K, ldc);
    };
    auto G64 = [&](const u16* A, const u16* Wt, const float* bi, void* C,
                   int K, int ldc, int out_bf) {
        dim3 grid(512 / 64, Tt / 128);
        if (out_bf) gemm64<1,0><<<grid, dim3(128), 0, stream>>>(A, Wt, bi, C, Tt, 512, K, ldc);
        else        gemm64<0,0><<<grid, dim3(128), 0, stream>>>(A, Wt, bi, C, Tt, 512, K, ldc);
    };
    const dim3 agrid(Sx / 128, Bx * Hx);    // (16, 32) = 512 blocks

    // ---- stage 1: fused QKV GEMM + self-attn + add&norm ----
    G128(xb, wsaq, sa_bq, sa_bk, sa_bv, sa_bv, qkvB, 1536, 512, 1536, 1, 0);
    attn_mfma<true><<<agrid, dim3(256), 0, stream>>>(qkvB, qkvB + 512, qkvB + 1024,
                                                     ob, 1536, 1536, 1536);
    G64(ob, wsao, sa_bo, projF, 512, 512, 0);
    ln_add<<<dim3(Tt), dim3(256), 0, stream>>>(x, projF, ln1_g, ln1_b, x1f, x1b);

    // ---- stage 2: cross-attention + add&norm ----
    G64(x1b, wcaq, ca_bq, qb, 512, 512, 1);
    G128(encb, wcak, ca_bk, ca_bv, ca_bv, ca_bv, kvB, 1024, 512, 1024, 1, 0);
    attn_mfma<false><<<agrid, dim3(256), 0, stream>>>(qb, kvB, kvB + 512,
                                                      ob, 512, 1024, 1024);
    G64(ob, wcao, ca_bo, projF, 512, 512, 0);
    ln_add<<<dim3(Tt), dim3(256), 0, stream>>>(x1f, projF, ln2_g, ln2_b, x2f, x2b);

    // ---- stage 3: FFN + add&norm ----
    G128(x2b, wff1, ff_b1, ff_b1 + 512, ff_b1 + 1024, ff_b1 + 1536,
         ff1b, 2048, 512, 2048, 1, 1);                       // ReLU
    G64(ff1b, wff2, ff_b2, projF, 2048, 512, 0);
    ln_add<<<dim3(Tt), dim3(256), 0, stream>>>(x2f, projF, ln3_g, ln3_b,
                                               (float*)d_out, (u16*)nullptr);
}